// Round 1
// baseline (560.443 us; speedup 1.0000x reference)
//
#include <hip/hip_runtime.h>
#include <hip/hip_bf16.h>

#define N_NODES 50000
#define N_EDGES 800000
#define NODE_F  128
#define EDGE_F  64
#define OUT_F   128
#define K_DIM   192           // EDGE_F + NODE_F
#define TILE_M  32
#define LDS_STRIDE 200        // bf16 elems/row; 100 dwords ≡ 4 (mod 32) → bank stride 4
#define N_TILES (N_EDGES / TILE_M)   // 25000 exact, no tail
#define NBLOCKS 2048

typedef __attribute__((ext_vector_type(8))) short short8;
typedef __attribute__((ext_vector_type(4))) short short4v;
typedef __attribute__((ext_vector_type(4))) float floatx4;

// round-to-nearest-even fp32 -> bf16 (inputs are finite randn, no NaN handling needed)
__device__ __forceinline__ unsigned short f2bf(float f) {
    unsigned int u = __float_as_uint(f);
    u += 0x7fffu + ((u >> 16) & 1u);
    return (unsigned short)(u >> 16);
}

__global__ __launch_bounds__(256, 4) void gnn_branch_kernel(
    const float* __restrict__ x,
    const int*   __restrict__ edge_index,
    const float* __restrict__ edge_attr,
    const float* __restrict__ W,
    const float* __restrict__ bias,
    float*       __restrict__ out)
{
    __shared__ __align__(16) unsigned short feats[TILE_M][LDS_STRIDE];
    __shared__ int dst_lds[TILE_M];

    const int tid  = threadIdx.x;
    const int wave = tid >> 6;
    const int lane = tid & 63;
    const int col  = lane & 15;
    const int quad = lane >> 4;
    const int wbase = wave * 32;     // this wave's N offset (covers 32 of 128 outputs)

    // ---- Load W into registers as bf16 B-fragments: [6 k-chunks][2 n-subtiles] ----
    // B-frag layout (16x16x32): lane holds B[k = kc*32 + quad*8 + j][n = nsub*16 + col]
    short8 bfr[6][2];
    #pragma unroll
    for (int kc = 0; kc < 6; ++kc) {
        #pragma unroll
        for (int ns = 0; ns < 2; ++ns) {
            const int n    = wbase + ns * 16 + col;
            const int krow = kc * 32 + quad * 8;
            short8 v;
            #pragma unroll
            for (int j = 0; j < 8; ++j)
                v[j] = (short)f2bf(W[(krow + j) * OUT_F + n]);
            bfr[kc][ns] = v;
        }
    }
    const float b0 = bias[wbase + col];
    const float b1 = bias[wbase + 16 + col];

    const int* __restrict__ srcp = edge_index;            // row 0: src
    const int* __restrict__ dstp = edge_index + N_EDGES;  // row 1: dst

    for (int tile = blockIdx.x; tile < N_TILES; tile += gridDim.x) {
        const int e0 = tile * TILE_M;

        // ---- stage dst indices ----
        if (tid < TILE_M) dst_lds[tid] = dstp[e0 + tid];

        // ---- stage feats[32][192] as bf16: 8 threads per edge, 6 float4 each ----
        {
            const int e   = tid >> 3;     // 0..31
            const int sub = tid & 7;      // 0..7
            const int src = srcp[e0 + e];
            const float* __restrict__ ea = edge_attr + (size_t)(e0 + e) * EDGE_F;
            const float* __restrict__ xr = x + (size_t)src * NODE_F;
            #pragma unroll
            for (int i = 0; i < 6; ++i) {
                const int fi = sub + 8 * i;   // float4 index 0..47 within the 192-row
                floatx4 v;
                if (fi < 16) v = *(const floatx4*)(ea + fi * 4);
                else         v = *(const floatx4*)(xr + (fi - 16) * 4);
                short4v sv;
                sv[0] = (short)f2bf(v[0]);
                sv[1] = (short)f2bf(v[1]);
                sv[2] = (short)f2bf(v[2]);
                sv[3] = (short)f2bf(v[3]);
                *(short4v*)&feats[e][fi * 4] = sv;
            }
        }
        __syncthreads();

        // ---- MFMA: [32 x 192] @ [192 x 32-per-wave] ----
        floatx4 acc[2][2] = {};
        #pragma unroll
        for (int kc = 0; kc < 6; ++kc) {
            // A-frag: lane holds feats[m = msub*16 + col][kc*32 + quad*8 + j], 16B contiguous
            short8 a0 = *(const short8*)&feats[col     ][kc * 32 + quad * 8];
            short8 a1 = *(const short8*)&feats[16 + col][kc * 32 + quad * 8];
            acc[0][0] = __builtin_amdgcn_mfma_f32_16x16x32_bf16(a0, bfr[kc][0], acc[0][0], 0, 0, 0);
            acc[0][1] = __builtin_amdgcn_mfma_f32_16x16x32_bf16(a0, bfr[kc][1], acc[0][1], 0, 0, 0);
            acc[1][0] = __builtin_amdgcn_mfma_f32_16x16x32_bf16(a1, bfr[kc][0], acc[1][0], 0, 0, 0);
            acc[1][1] = __builtin_amdgcn_mfma_f32_16x16x32_bf16(a1, bfr[kc][1], acc[1][1], 0, 0, 0);
        }

        // ---- epilogue: bias + ReLU + scatter-add ----
        // C/D layout: col = lane&15 (n), row = quad*4 + r (m)
        #pragma unroll
        for (int ms = 0; ms < 2; ++ms) {
            #pragma unroll
            for (int r = 0; r < 4; ++r) {
                const int m = ms * 16 + quad * 4 + r;
                const int d = dst_lds[m];
                float* orow = out + (size_t)d * OUT_F + wbase;
                const float v0 = acc[ms][0][r] + b0;
                const float v1 = acc[ms][1][r] + b1;
                if (v0 > 0.0f) atomicAdd(orow + col,      v0);   // ReLU: skip zeros
                if (v1 > 0.0f) atomicAdd(orow + 16 + col, v1);
            }
        }
        __syncthreads();   // protect feats/dst_lds before next tile's staging
    }
}

extern "C" void kernel_launch(void* const* d_in, const int* in_sizes, int n_in,
                              void* d_out, int out_size, void* d_ws, size_t ws_size,
                              hipStream_t stream) {
    const float* x          = (const float*)d_in[0];
    const int*   edge_index = (const int*)  d_in[1];
    const float* edge_attr  = (const float*)d_in[2];
    const float* W          = (const float*)d_in[3];
    const float* bias       = (const float*)d_in[4];
    float*       out        = (float*)d_out;

    // d_out is poisoned with 0xAA before every launch — zero it (scatter-add target)
    hipMemsetAsync(out, 0, (size_t)out_size * sizeof(float), stream);

    gnn_branch_kernel<<<dim3(NBLOCKS), dim3(256), 0, stream>>>(
        x, edge_index, edge_attr, W, bias, out);
}